// Round 1
// baseline (147.333 us; speedup 1.0000x reference)
//
#include <hip/hip_runtime.h>

// Problem constants (from reference): DIM=128, output = [1,128] float32.
// ws layout: [0]=int match counter; +64B: int mdst[CAP]; +64+4*CAP: int mfreq[CAP]
#define CAP 8192
#define DIM 128

__global__ void filter_edges_kernel(const int* __restrict__ user_idx,
                                    const int* __restrict__ edge_src,
                                    const int* __restrict__ edge_dst,
                                    const int* __restrict__ edge_freq,
                                    int E,
                                    int* __restrict__ count,
                                    int* __restrict__ mdst,
                                    int* __restrict__ mfreq) {
    const int uid = user_idx[0];
    const int gtid = blockIdx.x * blockDim.x + threadIdx.x;
    const int stride = gridDim.x * blockDim.x;
    const int E4 = E >> 2;
    const int4* __restrict__ src4 = (const int4*)edge_src;

    for (int i4 = gtid; i4 < E4; i4 += stride) {
        int4 s = src4[i4];
        if (s.x == uid || s.y == uid || s.z == uid || s.w == uid) {
            const int base = i4 * 4;
            int vals[4] = {s.x, s.y, s.z, s.w};
#pragma unroll
            for (int j = 0; j < 4; ++j) {
                if (vals[j] == uid) {
                    int p = atomicAdd(count, 1);
                    if (p < CAP) {
                        mdst[p]  = edge_dst[base + j];
                        mfreq[p] = edge_freq[base + j];
                    }
                }
            }
        }
    }
    // tail (E not multiple of 4)
    for (int i = E4 * 4 + gtid; i < E; i += stride) {
        if (edge_src[i] == uid) {
            int p = atomicAdd(count, 1);
            if (p < CAP) {
                mdst[p]  = edge_dst[i];
                mfreq[p] = edge_freq[i];
            }
        }
    }
}

__global__ void __launch_bounds__(DIM)
finish_kernel(const int* __restrict__ user_idx,
              const float* __restrict__ poi,       // [P, DIM]
              const float* __restrict__ user_emb,  // [U, DIM]
              const float* __restrict__ fc_w,      // [DIM, 2*DIM] row-major
              const float* __restrict__ fc_b,      // [DIM]
              const int* __restrict__ count,
              const int* __restrict__ mdst,
              const int* __restrict__ mfreq,
              float* __restrict__ out) {           // [DIM]
    __shared__ float comb[2 * DIM];
    const int d = threadIdx.x;  // 0..127

    int cnt = *count;
    if (cnt > CAP) cnt = CAP;

    float num = 0.0f;
    float den = 0.0f;
    for (int m = 0; m < cnt; ++m) {
        const float f = (float)mfreq[m];                 // broadcast (cached)
        num += f * poi[(size_t)mdst[m] * DIM + d];        // coalesced 512B row read
        den += f;
    }
    const float neigh = (den > 0.0f) ? (num / den) : 0.0f;

    const int uid = user_idx[0];
    comb[d]       = user_emb[(size_t)uid * DIM + d];
    comb[DIM + d] = neigh;
    __syncthreads();

    // out[d] = fc_b[d] + sum_k comb[k] * fc_w[d, k]
    const float4* __restrict__ w4 = (const float4*)(fc_w + (size_t)d * (2 * DIM));
    float acc = fc_b[d];
#pragma unroll 8
    for (int k = 0; k < (2 * DIM) / 4; ++k) {
        const float4 w = w4[k];
        acc += w.x * comb[4 * k + 0] + w.y * comb[4 * k + 1] +
               w.z * comb[4 * k + 2] + w.w * comb[4 * k + 3];
    }
    out[d] = acc;
}

extern "C" void kernel_launch(void* const* d_in, const int* in_sizes, int n_in,
                              void* d_out, int out_size, void* d_ws, size_t ws_size,
                              hipStream_t stream) {
    const int*   user_idx  = (const int*)d_in[0];
    const float* poi       = (const float*)d_in[1];
    const int*   edge_src  = (const int*)d_in[2];
    const int*   edge_dst  = (const int*)d_in[3];
    const int*   edge_freq = (const int*)d_in[4];
    const float* user_emb  = (const float*)d_in[5];
    const float* fc_w      = (const float*)d_in[6];
    const float* fc_b      = (const float*)d_in[7];
    float* out = (float*)d_out;

    const int E = in_sizes[2];

    char* ws = (char*)d_ws;
    int* count = (int*)ws;
    int* mdst  = (int*)(ws + 64);
    int* mfreq = (int*)(ws + 64 + 4 * CAP);

    // zero the match counter (ws is poisoned 0xAA before every timed launch)
    hipMemsetAsync(count, 0, sizeof(int), stream);

    const int threads = 256;
    const int E4 = E >> 2;
    int blocks = (E4 + threads - 1) / threads;
    if (blocks < 1) blocks = 1;
    if (blocks > 65535) blocks = 65535;

    filter_edges_kernel<<<blocks, threads, 0, stream>>>(
        user_idx, edge_src, edge_dst, edge_freq, E, count, mdst, mfreq);

    finish_kernel<<<1, DIM, 0, stream>>>(
        user_idx, poi, user_emb, fc_w, fc_b, count, mdst, mfreq, out);
}

// Round 2
// 135.432 us; speedup vs baseline: 1.0879x; 1.0879x over previous
//
#include <hip/hip_runtime.h>

#define DIM 128

// ws layout: float num[128] (512 B) | float den (at +512) ; memset first 640 B to 0.

__global__ void scan_accum_kernel(const int* __restrict__ user_idx,
                                  const int* __restrict__ edge_src,
                                  const int* __restrict__ edge_dst,
                                  const int* __restrict__ edge_freq,
                                  int E,
                                  const float* __restrict__ poi,   // [P, DIM]
                                  float* __restrict__ num,         // [DIM]
                                  float* __restrict__ den) {       // [1]
    const int uid = user_idx[0];
    const int lane = threadIdx.x & 63;
    const int gtid = blockIdx.x * blockDim.x + threadIdx.x;
    const int stride = gridDim.x * blockDim.x;
    const int E4 = E >> 2;
    const int4* __restrict__ src4 = (const int4*)edge_src;

    for (int i4 = gtid; i4 < E4; i4 += stride) {
        const int4 s = src4[i4];
        const bool any = (s.x == uid) | (s.y == uid) | (s.z == uid) | (s.w == uid);
        if (__any(any)) {                      // wave-uniform rare path
            const int base = i4 * 4;
            const int sv[4] = {s.x, s.y, s.z, s.w};
#pragma unroll
            for (int j = 0; j < 4; ++j) {
                const bool m = (sv[j] == uid);
                int dst = 0, f = 0;
                if (m) { dst = edge_dst[base + j]; f = edge_freq[base + j]; }
                unsigned long long b = __ballot(m);
                while (b) {
                    const int sl = (int)__ffsll(b) - 1;
                    b &= b - 1;
                    const int   ddst = __shfl(dst, sl);
                    const float fv   = (float)__shfl(f, sl);
                    // whole wave loads the 128-float row: 2 floats/lane, coalesced
                    const float* row = poi + (size_t)ddst * DIM;
                    const float v0 = row[lane];
                    const float v1 = row[lane + 64];
                    atomicAdd(&num[lane],      fv * v0);
                    atomicAdd(&num[lane + 64], fv * v1);
                    if (lane == 0) atomicAdd(den, fv);
                }
            }
        }
    }
    // tail (E not multiple of 4) — rare/absent (E=3.2M divisible by 4)
    for (int i = E4 * 4 + gtid; i < E; i += stride) {
        if (edge_src[i] == uid) {
            const float fv = (float)edge_freq[i];
            const float* row = poi + (size_t)edge_dst[i] * DIM;
            for (int k = 0; k < DIM; ++k) atomicAdd(&num[k], fv * row[k]);
            atomicAdd(den, fv);
        }
    }
}

__global__ void __launch_bounds__(DIM)
finish_kernel(const int* __restrict__ user_idx,
              const float* __restrict__ user_emb,  // [U, DIM]
              const float* __restrict__ fc_w,      // [DIM, 2*DIM] row-major
              const float* __restrict__ fc_b,      // [DIM]
              const float* __restrict__ num,       // [DIM]
              const float* __restrict__ den,       // [1]
              float* __restrict__ out) {           // [DIM]
    __shared__ float comb[2 * DIM];
    const int d = threadIdx.x;  // 0..127

    const float dv = *den;
    const float neigh = (dv > 0.0f) ? (num[d] / dv) : 0.0f;

    const int uid = user_idx[0];
    comb[d]       = user_emb[(size_t)uid * DIM + d];
    comb[DIM + d] = neigh;
    __syncthreads();

    const float4* __restrict__ w4 = (const float4*)(fc_w + (size_t)d * (2 * DIM));
    float acc = fc_b[d];
#pragma unroll 8
    for (int k = 0; k < (2 * DIM) / 4; ++k) {
        const float4 w = w4[k];
        acc += w.x * comb[4 * k + 0] + w.y * comb[4 * k + 1] +
               w.z * comb[4 * k + 2] + w.w * comb[4 * k + 3];
    }
    out[d] = acc;
}

extern "C" void kernel_launch(void* const* d_in, const int* in_sizes, int n_in,
                              void* d_out, int out_size, void* d_ws, size_t ws_size,
                              hipStream_t stream) {
    const int*   user_idx  = (const int*)d_in[0];
    const float* poi       = (const float*)d_in[1];
    const int*   edge_src  = (const int*)d_in[2];
    const int*   edge_dst  = (const int*)d_in[3];
    const int*   edge_freq = (const int*)d_in[4];
    const float* user_emb  = (const float*)d_in[5];
    const float* fc_w      = (const float*)d_in[6];
    const float* fc_b      = (const float*)d_in[7];
    float* out = (float*)d_out;

    const int E = in_sizes[2];

    char* ws = (char*)d_ws;
    float* num = (float*)ws;           // 128 floats
    float* den = (float*)(ws + 512);   // 1 float

    // zero the accumulators (ws is poisoned 0xAA before every timed launch)
    hipMemsetAsync(ws, 0, 640, stream);

    const int threads = 256;
    const int E4 = E >> 2;
    int blocks = (E4 + threads - 1) / threads;
    if (blocks < 1) blocks = 1;
    if (blocks > 65535) blocks = 65535;

    scan_accum_kernel<<<blocks, threads, 0, stream>>>(
        user_idx, edge_src, edge_dst, edge_freq, E, poi, num, den);

    finish_kernel<<<1, DIM, 0, stream>>>(
        user_idx, user_emb, fc_w, fc_b, num, den, out);
}